// Round 11
// baseline (242.999 us; speedup 1.0000x reference)
//
#include <hip/hip_runtime.h>

typedef _Float16 f16;
typedef _Float16 f16x4 __attribute__((ext_vector_type(4)));
typedef _Float16 f16x8 __attribute__((ext_vector_type(8)));
typedef float    f32x4 __attribute__((ext_vector_type(4)));

#define BATCH 65536
#define INDIM 512
#define MD    64
#define MSZ   100
#define NCAT  35
#define CKSZ  5
#define ODIM  512
#define N1    256    // X cols: [bq(64) | cq(64) | S_raw(100) | pad(28)]
#define NSLOT (NCAT*CKSZ)
#define RBS   264    // rb stride in f16; cols 0..255 live, 128..255 = GEMM2 A-panel

static __device__ __forceinline__ f32x4 mfma16(f16x4 a, f16x4 b, f32x4 c) {
  return __builtin_amdgcn_mfma_f32_16x16x16f16(a, b, c, 0, 0, 0);
}

// ===== prep: B1 plain [256][512] + bias1 | B2p frag-packed | C2cat =====
// B2p quad idx: ((otile*8 + kstep)*64 + lane)*4+j = B2[otile*16+(lane&15)][kstep*16+4*(lane>>4)+j]
//   B2[o][kk] = kk<100 ? base_vals[kk]·W_out[o,:64] : 0
__global__ __launch_bounds__(256) void k_prep(
    const float* __restrict__ Wb, const float* __restrict__ bb,
    const float* __restrict__ Wc, const float* __restrict__ bc,
    const float* __restrict__ keys, const float* __restrict__ bvals,
    const float* __restrict__ cvals, const float* __restrict__ Wo,
    f16* __restrict__ B1, float* __restrict__ bias1,
    f16* __restrict__ B2p, f16* __restrict__ C2cat) {
  int id = blockIdx.x * 256 + threadIdx.x;
  if (id < N1 * INDIM) {
    int k = id & (INDIM - 1);
    int n = id >> 9;
    float v = 0.f;
    if (n < 64) v = Wb[n * INDIM + k];
    else if (n < 128) v = Wc[(n - 64) * INDIM + k];
    else if (n < 128 + MSZ) {
      int m = n - 128;
      float s = 0.f;
      for (int d = 0; d < MD; d++) { float kv = keys[m * MD + d]; s += kv * kv; }
      float dn = fmaxf(sqrtf(s), 1e-8f);
      float a = 0.f;
      for (int d = 0; d < MD; d++) a += Wb[d * INDIM + k] * keys[m * MD + d];
      v = a / dn;
    }
    B1[n * INDIM + k] = (f16)v;
    if (k == 0) {
      float bv = 0.f;
      if (n < 64) bv = bb[n];
      else if (n < 128) bv = bc[n - 64];
      else if (n < 128 + MSZ) {
        int m = n - 128;
        float s = 0.f;
        for (int d = 0; d < MD; d++) { float kv = keys[m * MD + d]; s += kv * kv; }
        float dn = fmaxf(sqrtf(s), 1e-8f);
        float a = 0.f;
        for (int d = 0; d < MD; d++) a += bb[d] * keys[m * MD + d];
        bv = a / dn;
      }
      bias1[n] = bv;
    }
  } else if (id < N1 * INDIM + 16384) {
    int q2 = id - N1 * INDIM;
    int l = q2 & 63, otile = q2 >> 9;
    int o = otile * 16 + (l & 15);
    int kkb = ((q2 >> 6) & 7) * 16 + 4 * (l >> 4);
    float v0 = 0.f, v1 = 0.f, v2 = 0.f, v3 = 0.f;
    if (kkb < MSZ) {
      for (int d = 0; d < MD; d++) {
        float w = Wo[o * 128 + d];
        v0 += bvals[(kkb + 0) * MD + d] * w;
        v1 += bvals[(kkb + 1) * MD + d] * w;
        v2 += bvals[(kkb + 2) * MD + d] * w;
        v3 += bvals[(kkb + 3) * MD + d] * w;
      }
    }
    f16x4 o4; o4[0] = (f16)v0; o4[1] = (f16)v1; o4[2] = (f16)v2; o4[3] = (f16)v3;
    *(f16x4*)(B2p + (size_t)q2 * 4) = o4;
  } else if (id < N1 * INDIM + 16384 + NSLOT * ODIM) {
    int id3 = id - N1 * INDIM - 16384;
    int s = id3 >> 9, o = id3 & 511;
    float a = 0.f;
    for (int d = 0; d < MD; d++) a += cvals[s * MD + d] * Wo[o * 128 + 64 + d];
    C2cat[(size_t)s * ODIM + o] = (f16)a;
  }
}

// ===== fully fused: q -> out  (GEMM1 + softmax/mid + GEMM2 + cat gather) ====
__global__ __launch_bounds__(512, 4) void k_all(const float* __restrict__ q,
    const f16* __restrict__ B1, const float* __restrict__ bias1,
    const int* __restrict__ cidx, const float* __restrict__ catk,
    const f16* __restrict__ B2p, const f16* __restrict__ C2cat,
    const float* __restrict__ bout, float* __restrict__ out) {
  // union: K-loop staging (Al 10240B + Bl 20480B) aliases rb (128*264*2 B)
  __shared__ __align__(16) char smem[128 * RBS * 2];
  f16 (*Al)[40] = (f16(*)[40])smem;             // [128][40]
  f16 (*Bl)[40] = (f16(*)[40])(smem + 10240);   // [256][40]
  f16 (*rb)[RBS] = (f16(*)[RBS])smem;           // [128][264]
  __shared__ float cws[128][5];
  __shared__ int   csi[128];

  const int tid = threadIdx.x;
  const int lane = tid & 63, wid = tid >> 6;
  const int wm = wid & 1, wn = wid >> 1;
  const int row0 = blockIdx.x * 128;
  const int l15 = lane & 15, l4 = lane >> 4;
  f32x4 acc[4][4];
#pragma unroll
  for (int i = 0; i < 4; i++)
#pragma unroll
    for (int j = 0; j < 4; j++) acc[i][j] = (f32x4){0.f, 0.f, 0.f, 0.f};

  const int arow = tid >> 2, aseg = tid & 3;
  const int brow = tid >> 1, bh = tid & 1;

  // ---- phase 1: K-loop (round-1/9/10-validated structure) ----
  for (int k0 = 0; k0 < INDIM; k0 += 32) {
    const float* qp = q + (size_t)(row0 + arow) * INDIM + k0 + aseg * 8;
    f32x4 a0 = *(const f32x4*)qp;
    f32x4 a1 = *(const f32x4*)(qp + 4);
    f16x8 av;
#pragma unroll
    for (int i = 0; i < 4; i++) { av[i] = (f16)a0[i]; av[4 + i] = (f16)a1[i]; }
    const f16* bp = B1 + brow * INDIM + k0 + bh * 16;
    f16x8 bv0 = *(const f16x8*)bp;
    f16x8 bv1 = *(const f16x8*)(bp + 8);
    __syncthreads();
    *(f16x8*)&Al[arow][aseg * 8] = av;
    *(f16x8*)&Bl[brow][bh * 16] = bv0;
    *(f16x8*)&Bl[brow][bh * 16 + 8] = bv1;
    __syncthreads();
#pragma unroll
    for (int kk = 0; kk < 2; kk++) {
      const int kc = kk * 16 + 4 * l4;
      f16x4 af[4], bf[4];
#pragma unroll
      for (int mi = 0; mi < 4; mi++) af[mi] = *(const f16x4*)&Al[wm * 64 + mi * 16 + l15][kc];
#pragma unroll
      for (int ni = 0; ni < 4; ni++) bf[ni] = *(const f16x4*)&Bl[wn * 64 + ni * 16 + l15][kc];
#pragma unroll
      for (int mi = 0; mi < 4; mi++)
#pragma unroll
        for (int ni = 0; ni < 4; ni++)
          acc[mi][ni] = mfma16(af[mi], bf[ni], acc[mi][ni]);
    }
  }
  __syncthreads();   // all waves done reading Al/Bl before rb (alias) is written

  // ---- epilogue: acc -> rb cols 0..255 (cols 228..255 are exact zeros) ----
#pragma unroll
  for (int ni = 0; ni < 4; ni++) {
    const int col = wn * 64 + ni * 16 + l15;
    const float bs = bias1[col];
#pragma unroll
    for (int mi = 0; mi < 4; mi++) {
      const int r = wm * 64 + mi * 16 + 4 * l4;
#pragma unroll
      for (int j = 0; j < 4; j++)
        rb[r + j][col] = (f16)(acc[mi][ni][j] + bs);
    }
  }
  __syncthreads();

  // ---- phase 2: 4 threads/row softmaxes (round-9/10-validated), in-place --
  {
    const int row = tid >> 2, s = tid & 3;
    f16x8 v0 = *(const f16x8*)&rb[row][s * 16];
    f16x8 v1 = *(const f16x8*)&rb[row][s * 16 + 8];
    float nb = 0.f;
#pragma unroll
    for (int i = 0; i < 8; i++) { float x = (float)v0[i]; nb += x * x; }
#pragma unroll
    for (int i = 0; i < 8; i++) { float x = (float)v1[i]; nb += x * x; }
    nb += __shfl_xor(nb, 1, 64);
    nb += __shfl_xor(nb, 2, 64);
    const float rinv = 1.f / fmaxf(sqrtf(nb), 1e-8f);

    float sv[25];
#pragma unroll
    for (int i = 0; i < 25; i++)
      sv[i] = (float)rb[row][128 + s * 25 + i] * rinv;
    float mx = sv[0];
#pragma unroll
    for (int i = 1; i < 25; i++) mx = fmaxf(mx, sv[i]);
    mx = fmaxf(mx, __shfl_xor(mx, 1, 64));
    mx = fmaxf(mx, __shfl_xor(mx, 2, 64));
    float es = 0.f;
#pragma unroll
    for (int i = 0; i < 25; i++) { sv[i] = __expf(sv[i] - mx); es += sv[i]; }
    es += __shfl_xor(es, 1, 64);
    es += __shfl_xor(es, 2, 64);
    const float isum = 1.f / es;

    // category dots (reads cols 64..127, disjoint from attn writes)
    const int ci = cidx[row0 + row];
    const float* kp = catk + (size_t)ci * (CKSZ * MD) + s * 16;
    f16x8 c0 = *(const f16x8*)&rb[row][64 + s * 16];
    f16x8 c1 = *(const f16x8*)&rb[row][64 + s * 16 + 8];
    float cqf[16];
#pragma unroll
    for (int i = 0; i < 8; i++) { cqf[i] = (float)c0[i]; cqf[8 + i] = (float)c1[i]; }
    float t[5];
#pragma unroll
    for (int sl = 0; sl < 5; sl++) {
      f32x4 k0 = *(const f32x4*)(kp + sl * MD);
      f32x4 k1 = *(const f32x4*)(kp + sl * MD + 4);
      f32x4 k2 = *(const f32x4*)(kp + sl * MD + 8);
      f32x4 k3 = *(const f32x4*)(kp + sl * MD + 12);
      float a = 0.f;
#pragma unroll
      for (int i = 0; i < 4; i++) a += cqf[i] * k0[i];
#pragma unroll
      for (int i = 0; i < 4; i++) a += cqf[4 + i] * k1[i];
#pragma unroll
      for (int i = 0; i < 4; i++) a += cqf[8 + i] * k2[i];
#pragma unroll
      for (int i = 0; i < 4; i++) a += cqf[12 + i] * k3[i];
      a += __shfl_xor(a, 1, 64);
      a += __shfl_xor(a, 2, 64);
      t[sl] = a;
    }

    // in-place: attn over own sims slice (cols 128..227)
#pragma unroll
    for (int i = 0; i < 25; i++)
      rb[row][128 + s * 25 + i] = (f16)(sv[i] * isum);

    if (s == 0) {
      float m5 = fmaxf(fmaxf(fmaxf(t[0], t[1]), fmaxf(t[2], t[3])), t[4]);
      float e0 = __expf(t[0] - m5), e1 = __expf(t[1] - m5), e2 = __expf(t[2] - m5),
            e3 = __expf(t[3] - m5), e4 = __expf(t[4] - m5);
      float ics = 1.f / (e0 + e1 + e2 + e3 + e4);
      cws[row][0] = e0 * ics; cws[row][1] = e1 * ics; cws[row][2] = e2 * ics;
      cws[row][3] = e3 * ics; cws[row][4] = e4 * ics;
      csi[row] = ci * CKSZ;
    }
  }
  __syncthreads();

  // ---- phase 3: out = attn @ B2^T + bout + rank-5 cat gather ----
  // A-panel: rb cols 128..255 (attn 0..99, exact zeros 100..127). No barriers.
  for (int cpass = 0; cpass < 2; cpass++) {
    const int col0 = cpass * 256;
#pragma unroll
    for (int i = 0; i < 4; i++)
#pragma unroll
      for (int j = 0; j < 4; j++) acc[i][j] = (f32x4){0.f, 0.f, 0.f, 0.f};
#pragma unroll
    for (int ks = 0; ks < 8; ks++) {
      f16x4 af[4], bf[4];
#pragma unroll
      for (int mi = 0; mi < 4; mi++)
        af[mi] = *(const f16x4*)&rb[wm * 64 + mi * 16 + l15][128 + ks * 16 + 4 * l4];
#pragma unroll
      for (int ni = 0; ni < 4; ni++)
        bf[ni] = *(const f16x4*)(B2p +
          (((size_t)(cpass * 16 + wn * 4 + ni) * 8 + ks) * 64 + lane) * 4);
#pragma unroll
      for (int mi = 0; mi < 4; mi++)
#pragma unroll
        for (int ni = 0; ni < 4; ni++)
          acc[mi][ni] = mfma16(af[mi], bf[ni], acc[mi][ni]);
    }
    float bs[4];
#pragma unroll
    for (int ni = 0; ni < 4; ni++) bs[ni] = bout[col0 + wn * 64 + ni * 16 + l15];
#pragma unroll
    for (int mi = 0; mi < 4; mi++) {
#pragma unroll
      for (int j = 0; j < 4; j++) {
        const int r = wm * 64 + mi * 16 + 4 * l4 + j;
        const int cb = csi[r];
        const float w0 = cws[r][0], w1 = cws[r][1], w2 = cws[r][2],
                    w3 = cws[r][3], w4 = cws[r][4];
        const f16* cp = C2cat + (size_t)cb * ODIM + col0 + wn * 64 + l15;
#pragma unroll
        for (int ni = 0; ni < 4; ni++) {
          const int col = col0 + wn * 64 + ni * 16 + l15;
          const f16* cpn = cp + ni * 16;
          float v = acc[mi][ni][j] + bs[ni];
          v += w0 * (float)cpn[0]
             + w1 * (float)cpn[ODIM]
             + w2 * (float)cpn[2 * ODIM]
             + w3 * (float)cpn[3 * ODIM]
             + w4 * (float)cpn[4 * ODIM];
          out[(size_t)(row0 + r) * ODIM + col] = v;
        }
      }
    }
  }
}

extern "C" void kernel_launch(void* const* d_in, const int* in_sizes, int n_in,
                              void* d_out, int out_size, void* d_ws, size_t ws_size,
                              hipStream_t stream) {
  const float* query = (const float*)d_in[0];
  const int*   cidx  = (const int*)d_in[1];
  const float* Wb    = (const float*)d_in[2];
  const float* bb    = (const float*)d_in[3];
  const float* Wc    = (const float*)d_in[4];
  const float* bc    = (const float*)d_in[5];
  const float* bkeys = (const float*)d_in[6];
  const float* bvals = (const float*)d_in[7];
  const float* ckeys = (const float*)d_in[8];
  const float* cvals = (const float*)d_in[9];
  const float* Wo    = (const float*)d_in[10];
  const float* bo    = (const float*)d_in[11];
  float* out = (float*)d_out;

  char* ws = (char*)d_ws;
  f16*   B1    = (f16*)(ws);                          // 256*512*2 = 262144
  f16*   B2p   = (f16*)(ws + 262144);                 // 16384*4*2 = 131072
  f16*   C2cat = (f16*)(ws + 262144 + 131072);        // 175*512*2 = 179200
  float* bias1 = (float*)(ws + 262144 + 131072 + 179200);  // 1024

  const int prep_ids = N1 * INDIM + 16384 + NSLOT * ODIM;  // 237056
  k_prep<<<dim3((prep_ids + 255) / 256), 256, 0, stream>>>(
      Wb, bb, Wc, bc, bkeys, bvals, cvals, Wo, B1, bias1, B2p, C2cat);
  k_all<<<dim3(BATCH / 128), 512, 0, stream>>>(
      query, B1, bias1, cidx, ckeys, B2p, C2cat, bo, out);
}

// Round 12
// 204.582 us; speedup vs baseline: 1.1878x; 1.1878x over previous
//
#include <hip/hip_runtime.h>

typedef _Float16 f16;
typedef _Float16 f16x4 __attribute__((ext_vector_type(4)));
typedef _Float16 f16x8 __attribute__((ext_vector_type(8)));
typedef float    f32x4 __attribute__((ext_vector_type(4)));

#define BATCH 65536
#define INDIM 512
#define MD    64
#define MSZ   100
#define NCAT  35
#define CKSZ  5
#define ODIM  512
#define N1    256    // X cols: [bq(64) | cq(64) | S_raw(100) | pad(28)]
#define NSLOT (NCAT*CKSZ)
#define RBS   264    // rb stride in f16; cols 0..255 live, 128..255 = GEMM2 A-panel

static __device__ __forceinline__ f32x4 mfma16(f16x4 a, f16x4 b, f32x4 c) {
  return __builtin_amdgcn_mfma_f32_16x16x16f16(a, b, c, 0, 0, 0);
}

// ===== prep: B1 plain [256][512] + bias1 | B2p frag-packed | C2cat =====
// B2p quad idx: ((otile*8 + kstep)*64 + lane)*4+j = B2[otile*16+(lane&15)][kstep*16+4*(lane>>4)+j]
//   B2[o][kk] = kk<100 ? base_vals[kk]·W_out[o,:64] : 0
__global__ __launch_bounds__(256) void k_prep(
    const float* __restrict__ Wb, const float* __restrict__ bb,
    const float* __restrict__ Wc, const float* __restrict__ bc,
    const float* __restrict__ keys, const float* __restrict__ bvals,
    const float* __restrict__ cvals, const float* __restrict__ Wo,
    f16* __restrict__ B1, float* __restrict__ bias1,
    f16* __restrict__ B2p, f16* __restrict__ C2cat) {
  int id = blockIdx.x * 256 + threadIdx.x;
  if (id < N1 * INDIM) {
    int k = id & (INDIM - 1);
    int n = id >> 9;
    float v = 0.f;
    if (n < 64) v = Wb[n * INDIM + k];
    else if (n < 128) v = Wc[(n - 64) * INDIM + k];
    else if (n < 128 + MSZ) {
      int m = n - 128;
      float s = 0.f;
      for (int d = 0; d < MD; d++) { float kv = keys[m * MD + d]; s += kv * kv; }
      float dn = fmaxf(sqrtf(s), 1e-8f);
      float a = 0.f;
      for (int d = 0; d < MD; d++) a += Wb[d * INDIM + k] * keys[m * MD + d];
      v = a / dn;
    }
    B1[n * INDIM + k] = (f16)v;
    if (k == 0) {
      float bv = 0.f;
      if (n < 64) bv = bb[n];
      else if (n < 128) bv = bc[n - 64];
      else if (n < 128 + MSZ) {
        int m = n - 128;
        float s = 0.f;
        for (int d = 0; d < MD; d++) { float kv = keys[m * MD + d]; s += kv * kv; }
        float dn = fmaxf(sqrtf(s), 1e-8f);
        float a = 0.f;
        for (int d = 0; d < MD; d++) a += bb[d] * keys[m * MD + d];
        bv = a / dn;
      }
      bias1[n] = bv;
    }
  } else if (id < N1 * INDIM + 16384) {
    int q2 = id - N1 * INDIM;
    int l = q2 & 63, otile = q2 >> 9;
    int o = otile * 16 + (l & 15);
    int kkb = ((q2 >> 6) & 7) * 16 + 4 * (l >> 4);
    float v0 = 0.f, v1 = 0.f, v2 = 0.f, v3 = 0.f;
    if (kkb < MSZ) {
      for (int d = 0; d < MD; d++) {
        float w = Wo[o * 128 + d];
        v0 += bvals[(kkb + 0) * MD + d] * w;
        v1 += bvals[(kkb + 1) * MD + d] * w;
        v2 += bvals[(kkb + 2) * MD + d] * w;
        v3 += bvals[(kkb + 3) * MD + d] * w;
      }
    }
    f16x4 o4; o4[0] = (f16)v0; o4[1] = (f16)v1; o4[2] = (f16)v2; o4[3] = (f16)v3;
    *(f16x4*)(B2p + (size_t)q2 * 4) = o4;
  } else if (id < N1 * INDIM + 16384 + NSLOT * ODIM) {
    int id3 = id - N1 * INDIM - 16384;
    int s = id3 >> 9, o = id3 & 511;
    float a = 0.f;
    for (int d = 0; d < MD; d++) a += cvals[s * MD + d] * Wo[o * 128 + 64 + d];
    C2cat[(size_t)s * ODIM + o] = (f16)a;
  }
}

// ===== fully fused: q -> out  (GEMM1 + softmax/mid + GEMM2 + cat gather) ====
__global__ __launch_bounds__(512) void k_all(const float* __restrict__ q,
    const f16* __restrict__ B1, const float* __restrict__ bias1,
    const int* __restrict__ cidx, const float* __restrict__ catk,
    const f16* __restrict__ B2p, const f16* __restrict__ C2cat,
    const float* __restrict__ bout, float* __restrict__ out) {
  // union: K-loop staging (Al 10240B + Bl 20480B) aliases rb (128*264*2 B)
  __shared__ __align__(16) char smem[128 * RBS * 2];
  f16 (*Al)[40] = (f16(*)[40])smem;             // [128][40]
  f16 (*Bl)[40] = (f16(*)[40])(smem + 10240);   // [256][40]
  f16 (*rb)[RBS] = (f16(*)[RBS])smem;           // [128][264]
  __shared__ float cws[128][5];
  __shared__ int   csi[128];

  const int tid = threadIdx.x;
  const int lane = tid & 63, wid = tid >> 6;
  const int wm = wid & 1, wn = wid >> 1;
  const int row0 = blockIdx.x * 128;
  const int l15 = lane & 15, l4 = lane >> 4;
  f32x4 acc[4][4];
#pragma unroll
  for (int i = 0; i < 4; i++)
#pragma unroll
    for (int j = 0; j < 4; j++) acc[i][j] = (f32x4){0.f, 0.f, 0.f, 0.f};

  const int arow = tid >> 2, aseg = tid & 3;
  const int brow = tid >> 1, bh = tid & 1;

  // ---- phase 1: K-loop (round-1/9/10-validated structure) ----
  for (int k0 = 0; k0 < INDIM; k0 += 32) {
    const float* qp = q + (size_t)(row0 + arow) * INDIM + k0 + aseg * 8;
    f32x4 a0 = *(const f32x4*)qp;
    f32x4 a1 = *(const f32x4*)(qp + 4);
    f16x8 av;
#pragma unroll
    for (int i = 0; i < 4; i++) { av[i] = (f16)a0[i]; av[4 + i] = (f16)a1[i]; }
    const f16* bp = B1 + brow * INDIM + k0 + bh * 16;
    f16x8 bv0 = *(const f16x8*)bp;
    f16x8 bv1 = *(const f16x8*)(bp + 8);
    __syncthreads();
    *(f16x8*)&Al[arow][aseg * 8] = av;
    *(f16x8*)&Bl[brow][bh * 16] = bv0;
    *(f16x8*)&Bl[brow][bh * 16 + 8] = bv1;
    __syncthreads();
#pragma unroll
    for (int kk = 0; kk < 2; kk++) {
      const int kc = kk * 16 + 4 * l4;
      f16x4 af[4], bf[4];
#pragma unroll
      for (int mi = 0; mi < 4; mi++) af[mi] = *(const f16x4*)&Al[wm * 64 + mi * 16 + l15][kc];
#pragma unroll
      for (int ni = 0; ni < 4; ni++) bf[ni] = *(const f16x4*)&Bl[wn * 64 + ni * 16 + l15][kc];
#pragma unroll
      for (int mi = 0; mi < 4; mi++)
#pragma unroll
        for (int ni = 0; ni < 4; ni++)
          acc[mi][ni] = mfma16(af[mi], bf[ni], acc[mi][ni]);
    }
  }
  __syncthreads();   // all waves done reading Al/Bl before rb (alias) is written

  // ---- epilogue: acc -> rb cols 0..255 (cols 228..255 are exact zeros) ----
#pragma unroll
  for (int ni = 0; ni < 4; ni++) {
    const int col = wn * 64 + ni * 16 + l15;
    const float bs = bias1[col];
#pragma unroll
    for (int mi = 0; mi < 4; mi++) {
      const int r = wm * 64 + mi * 16 + 4 * l4;
#pragma unroll
      for (int j = 0; j < 4; j++)
        rb[r + j][col] = (f16)(acc[mi][ni][j] + bs);
    }
  }
  __syncthreads();

  // ---- phase 2: 4 threads/row softmaxes (round-9/10-validated), in-place --
  {
    const int row = tid >> 2, s = tid & 3;
    f16x8 v0 = *(const f16x8*)&rb[row][s * 16];
    f16x8 v1 = *(const f16x8*)&rb[row][s * 16 + 8];
    float nb = 0.f;
#pragma unroll
    for (int i = 0; i < 8; i++) { float x = (float)v0[i]; nb += x * x; }
#pragma unroll
    for (int i = 0; i < 8; i++) { float x = (float)v1[i]; nb += x * x; }
    nb += __shfl_xor(nb, 1, 64);
    nb += __shfl_xor(nb, 2, 64);
    const float rinv = 1.f / fmaxf(sqrtf(nb), 1e-8f);

    float sv[25];
#pragma unroll
    for (int i = 0; i < 25; i++)
      sv[i] = (float)rb[row][128 + s * 25 + i] * rinv;
    float mx = sv[0];
#pragma unroll
    for (int i = 1; i < 25; i++) mx = fmaxf(mx, sv[i]);
    mx = fmaxf(mx, __shfl_xor(mx, 1, 64));
    mx = fmaxf(mx, __shfl_xor(mx, 2, 64));
    float es = 0.f;
#pragma unroll
    for (int i = 0; i < 25; i++) { sv[i] = __expf(sv[i] - mx); es += sv[i]; }
    es += __shfl_xor(es, 1, 64);
    es += __shfl_xor(es, 2, 64);
    const float isum = 1.f / es;

    // category dots (reads cols 64..127, disjoint from attn writes)
    const int ci = cidx[row0 + row];
    const float* kp = catk + (size_t)ci * (CKSZ * MD) + s * 16;
    f16x8 c0 = *(const f16x8*)&rb[row][64 + s * 16];
    f16x8 c1 = *(const f16x8*)&rb[row][64 + s * 16 + 8];
    float cqf[16];
#pragma unroll
    for (int i = 0; i < 8; i++) { cqf[i] = (float)c0[i]; cqf[8 + i] = (float)c1[i]; }
    float t[5];
#pragma unroll
    for (int sl = 0; sl < 5; sl++) {
      f32x4 k0 = *(const f32x4*)(kp + sl * MD);
      f32x4 k1 = *(const f32x4*)(kp + sl * MD + 4);
      f32x4 k2 = *(const f32x4*)(kp + sl * MD + 8);
      f32x4 k3 = *(const f32x4*)(kp + sl * MD + 12);
      float a = 0.f;
#pragma unroll
      for (int i = 0; i < 4; i++) a += cqf[i] * k0[i];
#pragma unroll
      for (int i = 0; i < 4; i++) a += cqf[4 + i] * k1[i];
#pragma unroll
      for (int i = 0; i < 4; i++) a += cqf[8 + i] * k2[i];
#pragma unroll
      for (int i = 0; i < 4; i++) a += cqf[12 + i] * k3[i];
      a += __shfl_xor(a, 1, 64);
      a += __shfl_xor(a, 2, 64);
      t[sl] = a;
    }

    // in-place: attn over own sims slice (cols 128..227)
#pragma unroll
    for (int i = 0; i < 25; i++)
      rb[row][128 + s * 25 + i] = (f16)(sv[i] * isum);

    if (s == 0) {
      float m5 = fmaxf(fmaxf(fmaxf(t[0], t[1]), fmaxf(t[2], t[3])), t[4]);
      float e0 = __expf(t[0] - m5), e1 = __expf(t[1] - m5), e2 = __expf(t[2] - m5),
            e3 = __expf(t[3] - m5), e4 = __expf(t[4] - m5);
      float ics = 1.f / (e0 + e1 + e2 + e3 + e4);
      cws[row][0] = e0 * ics; cws[row][1] = e1 * ics; cws[row][2] = e2 * ics;
      cws[row][3] = e3 * ics; cws[row][4] = e4 * ics;
      csi[row] = ci * CKSZ;
    }
  }
  __syncthreads();

  // ---- phase 3: out = attn @ B2^T + bout + rank-5 cat gather ----
  // A-panel: rb cols 128..255 (attn 0..99, exact zeros 100..127). No barriers.
  for (int cpass = 0; cpass < 2; cpass++) {
    const int col0 = cpass * 256;
#pragma unroll
    for (int i = 0; i < 4; i++)
#pragma unroll
      for (int j = 0; j < 4; j++) acc[i][j] = (f32x4){0.f, 0.f, 0.f, 0.f};
#pragma unroll
    for (int ks = 0; ks < 8; ks++) {
      f16x4 af[4], bf[4];
#pragma unroll
      for (int mi = 0; mi < 4; mi++)
        af[mi] = *(const f16x4*)&rb[wm * 64 + mi * 16 + l15][128 + ks * 16 + 4 * l4];
#pragma unroll
      for (int ni = 0; ni < 4; ni++)
        bf[ni] = *(const f16x4*)(B2p +
          (((size_t)(cpass * 16 + wn * 4 + ni) * 8 + ks) * 64 + lane) * 4);
#pragma unroll
      for (int mi = 0; mi < 4; mi++)
#pragma unroll
        for (int ni = 0; ni < 4; ni++)
          acc[mi][ni] = mfma16(af[mi], bf[ni], acc[mi][ni]);
    }
    float bs[4];
#pragma unroll
    for (int ni = 0; ni < 4; ni++) bs[ni] = bout[col0 + wn * 64 + ni * 16 + l15];
#pragma unroll
    for (int mi = 0; mi < 4; mi++) {
#pragma unroll
      for (int j = 0; j < 4; j++) {
        const int r = wm * 64 + mi * 16 + 4 * l4 + j;
        const int cb = csi[r];
        const float w0 = cws[r][0], w1 = cws[r][1], w2 = cws[r][2],
                    w3 = cws[r][3], w4 = cws[r][4];
        const f16* cp = C2cat + (size_t)cb * ODIM + col0 + wn * 64 + l15;
#pragma unroll
        for (int ni = 0; ni < 4; ni++) {
          const int col = col0 + wn * 64 + ni * 16 + l15;
          const f16* cpn = cp + ni * 16;
          float v = acc[mi][ni][j] + bs[ni];
          v += w0 * (float)cpn[0]
             + w1 * (float)cpn[ODIM]
             + w2 * (float)cpn[2 * ODIM]
             + w3 * (float)cpn[3 * ODIM]
             + w4 * (float)cpn[4 * ODIM];
          out[(size_t)(row0 + r) * ODIM + col] = v;
        }
      }
    }
  }
}

extern "C" void kernel_launch(void* const* d_in, const int* in_sizes, int n_in,
                              void* d_out, int out_size, void* d_ws, size_t ws_size,
                              hipStream_t stream) {
  const float* query = (const float*)d_in[0];
  const int*   cidx  = (const int*)d_in[1];
  const float* Wb    = (const float*)d_in[2];
  const float* bb    = (const float*)d_in[3];
  const float* Wc    = (const float*)d_in[4];
  const float* bc    = (const float*)d_in[5];
  const float* bkeys = (const float*)d_in[6];
  const float* bvals = (const float*)d_in[7];
  const float* ckeys = (const float*)d_in[8];
  const float* cvals = (const float*)d_in[9];
  const float* Wo    = (const float*)d_in[10];
  const float* bo    = (const float*)d_in[11];
  float* out = (float*)d_out;

  char* ws = (char*)d_ws;
  f16*   B1    = (f16*)(ws);                          // 256*512*2 = 262144
  f16*   B2p   = (f16*)(ws + 262144);                 // 16384*4*2 = 131072
  f16*   C2cat = (f16*)(ws + 262144 + 131072);        // 175*512*2 = 179200
  float* bias1 = (float*)(ws + 262144 + 131072 + 179200);  // 1024

  const int prep_ids = N1 * INDIM + 16384 + NSLOT * ODIM;  // 237056
  k_prep<<<dim3((prep_ids + 255) / 256), 256, 0, stream>>>(
      Wb, bb, Wc, bc, bkeys, bvals, cvals, Wo, B1, bias1, B2p, C2cat);
  k_all<<<dim3(BATCH / 128), 512, 0, stream>>>(
      query, B1, bias1, cidx, ckeys, B2p, C2cat, bo, out);
}

// Round 13
// 107.397 us; speedup vs baseline: 2.2626x; 1.9049x over previous
//
#include <hip/hip_runtime.h>

typedef _Float16 f16;
typedef _Float16 f16x4 __attribute__((ext_vector_type(4)));
typedef _Float16 f16x8 __attribute__((ext_vector_type(8)));
typedef float    f32x4 __attribute__((ext_vector_type(4)));

#define BATCH 65536
#define INDIM 512
#define MD    64
#define MSZ   100
#define NCAT  35
#define CKSZ  5
#define ODIM  512
#define N1    256    // X cols: [bq(64) | cq(64) | S_raw(100) | pad(28)]
#define K2    128    // GEMM2 K: base attn 100 zero-padded to 128
#define NSLOT (NCAT*CKSZ)
#define RBS   232    // rb stride in f16 (cols 0..227 used)

static __device__ __forceinline__ f32x4 mfma16(f16x4 a, f16x4 b, f32x4 c) {
  return __builtin_amdgcn_mfma_f32_16x16x16f16(a, b, c, 0, 0, 0);
}

// ===== prep: B1 plain [256][512] + bias1 | B2p frag-packed | C2cat =====
// B2p quad idx: ((otile*8 + kstep)*64 + lane)*4+j = B2[otile*16+(lane&15)][kstep*16+4*(lane>>4)+j]
//   B2[o][kk] = kk<100 ? base_vals[kk]·W_out[o,:64] : 0
__global__ __launch_bounds__(256) void k_prep(
    const float* __restrict__ Wb, const float* __restrict__ bb,
    const float* __restrict__ Wc, const float* __restrict__ bc,
    const float* __restrict__ keys, const float* __restrict__ bvals,
    const float* __restrict__ cvals, const float* __restrict__ Wo,
    f16* __restrict__ B1, float* __restrict__ bias1,
    f16* __restrict__ B2p, f16* __restrict__ C2cat) {
  int id = blockIdx.x * 256 + threadIdx.x;
  if (id < N1 * INDIM) {
    int k = id & (INDIM - 1);
    int n = id >> 9;
    float v = 0.f;
    if (n < 64) v = Wb[n * INDIM + k];
    else if (n < 128) v = Wc[(n - 64) * INDIM + k];
    else if (n < 128 + MSZ) {
      int m = n - 128;
      float s = 0.f;
      for (int d = 0; d < MD; d++) { float kv = keys[m * MD + d]; s += kv * kv; }
      float dn = fmaxf(sqrtf(s), 1e-8f);
      float a = 0.f;
      for (int d = 0; d < MD; d++) a += Wb[d * INDIM + k] * keys[m * MD + d];
      v = a / dn;
    }
    B1[n * INDIM + k] = (f16)v;
    if (k == 0) {
      float bv = 0.f;
      if (n < 64) bv = bb[n];
      else if (n < 128) bv = bc[n - 64];
      else if (n < 128 + MSZ) {
        int m = n - 128;
        float s = 0.f;
        for (int d = 0; d < MD; d++) { float kv = keys[m * MD + d]; s += kv * kv; }
        float dn = fmaxf(sqrtf(s), 1e-8f);
        float a = 0.f;
        for (int d = 0; d < MD; d++) a += bb[d] * keys[m * MD + d];
        bv = a / dn;
      }
      bias1[n] = bv;
    }
  } else if (id < N1 * INDIM + 16384) {
    int q2 = id - N1 * INDIM;
    int l = q2 & 63, otile = q2 >> 9;
    int o = otile * 16 + (l & 15);
    int kkb = ((q2 >> 6) & 7) * 16 + 4 * (l >> 4);
    float v0 = 0.f, v1 = 0.f, v2 = 0.f, v3 = 0.f;
    if (kkb < MSZ) {
      for (int d = 0; d < MD; d++) {
        float w = Wo[o * 128 + d];
        v0 += bvals[(kkb + 0) * MD + d] * w;
        v1 += bvals[(kkb + 1) * MD + d] * w;
        v2 += bvals[(kkb + 2) * MD + d] * w;
        v3 += bvals[(kkb + 3) * MD + d] * w;
      }
    }
    f16x4 o4; o4[0] = (f16)v0; o4[1] = (f16)v1; o4[2] = (f16)v2; o4[3] = (f16)v3;
    *(f16x4*)(B2p + (size_t)q2 * 4) = o4;
  } else if (id < N1 * INDIM + 16384 + NSLOT * ODIM) {
    int id3 = id - N1 * INDIM - 16384;
    int s = id3 >> 9, o = id3 & 511;
    float a = 0.f;
    for (int d = 0; d < MD; d++) a += cvals[s * MD + d] * Wo[o * 128 + 64 + d];
    C2cat[(size_t)s * ODIM + o] = (f16)a;
  }
}

// ===== fused GEMM1+mid: q -> (A2, cw, cs)  M=65536,K=512,N=256 =====
// K-step 64: 8 iterations x 2 barriers (vs round-10's 16x2)
__global__ __launch_bounds__(512) void k_g1mid(const float* __restrict__ q,
    const f16* __restrict__ B1, const float* __restrict__ bias1,
    const int* __restrict__ cidx, const float* __restrict__ catk,
    f16* __restrict__ A2, float* __restrict__ cwg, int* __restrict__ csg) {
  // union: K-loop staging (Al 18432B + Bl 36864B = 55296B) aliases rb (59392B)
  __shared__ __align__(16) char smem[128 * RBS * 2];
  f16 (*Al)[72] = (f16(*)[72])smem;             // [128][72]
  f16 (*Bl)[72] = (f16(*)[72])(smem + 18432);   // [256][72]
  f16 (*rb)[RBS] = (f16(*)[RBS])smem;           // [128][232]

  const int tid = threadIdx.x;
  const int lane = tid & 63, wid = tid >> 6;
  const int wm = wid & 1, wn = wid >> 1;
  const int row0 = blockIdx.x * 128;
  const int l15 = lane & 15, l4 = lane >> 4;
  f32x4 acc[4][4];
#pragma unroll
  for (int i = 0; i < 4; i++)
#pragma unroll
    for (int j = 0; j < 4; j++) acc[i][j] = (f32x4){0.f, 0.f, 0.f, 0.f};

  const int arow = tid >> 2, aseg = tid & 3;   // A: 128 rows, 4x16 col segs
  const int brow = tid >> 1, bh = tid & 1;     // B: 256 rows, 2x32 col halves

  // ---- phase 1 K-loop: K-step 64 ----
  for (int k0 = 0; k0 < INDIM; k0 += 64) {
    const float* qp = q + (size_t)(row0 + arow) * INDIM + k0 + aseg * 16;
    f32x4 a0 = *(const f32x4*)qp;
    f32x4 a1 = *(const f32x4*)(qp + 4);
    f32x4 a2 = *(const f32x4*)(qp + 8);
    f32x4 a3 = *(const f32x4*)(qp + 12);
    f16x8 av0, av1;
#pragma unroll
    for (int i = 0; i < 4; i++) { av0[i] = (f16)a0[i]; av0[4 + i] = (f16)a1[i]; }
#pragma unroll
    for (int i = 0; i < 4; i++) { av1[i] = (f16)a2[i]; av1[4 + i] = (f16)a3[i]; }
    const f16* bp = B1 + brow * INDIM + k0 + bh * 32;
    f16x8 bv0 = *(const f16x8*)(bp);
    f16x8 bv1 = *(const f16x8*)(bp + 8);
    f16x8 bv2 = *(const f16x8*)(bp + 16);
    f16x8 bv3 = *(const f16x8*)(bp + 24);
    __syncthreads();
    *(f16x8*)&Al[arow][aseg * 16]     = av0;
    *(f16x8*)&Al[arow][aseg * 16 + 8] = av1;
    *(f16x8*)&Bl[brow][bh * 32]      = bv0;
    *(f16x8*)&Bl[brow][bh * 32 + 8]  = bv1;
    *(f16x8*)&Bl[brow][bh * 32 + 16] = bv2;
    *(f16x8*)&Bl[brow][bh * 32 + 24] = bv3;
    __syncthreads();
#pragma unroll
    for (int kk = 0; kk < 4; kk++) {
      const int kc = kk * 16 + 4 * l4;
      f16x4 af[4], bf[4];
#pragma unroll
      for (int mi = 0; mi < 4; mi++) af[mi] = *(const f16x4*)&Al[wm * 64 + mi * 16 + l15][kc];
#pragma unroll
      for (int ni = 0; ni < 4; ni++) bf[ni] = *(const f16x4*)&Bl[wn * 64 + ni * 16 + l15][kc];
#pragma unroll
      for (int mi = 0; mi < 4; mi++)
#pragma unroll
        for (int ni = 0; ni < 4; ni++)
          acc[mi][ni] = mfma16(af[mi], bf[ni], acc[mi][ni]);
    }
  }
  __syncthreads();   // all waves done reading Al/Bl before rb (alias) is written

  // ---- epilogue: acc -> rb (X rows in LDS; cols >= RBS unused) ----
#pragma unroll
  for (int ni = 0; ni < 4; ni++) {
    const int col = wn * 64 + ni * 16 + l15;
    const float bs = bias1[col];
    if (col < RBS) {
#pragma unroll
      for (int mi = 0; mi < 4; mi++) {
        const int r = wm * 64 + mi * 16 + 4 * l4;
#pragma unroll
        for (int j = 0; j < 4; j++)
          rb[r + j][col] = (f16)(acc[mi][ni][j] + bs);
      }
    }
  }
  __syncthreads();

  // ---- mid: 4 threads/row softmaxes (round-9/10-validated), in-place attn --
  {
    const int row = tid >> 2, s = tid & 3;
    f16x8 v0 = *(const f16x8*)&rb[row][s * 16];
    f16x8 v1 = *(const f16x8*)&rb[row][s * 16 + 8];
    float nb = 0.f;
#pragma unroll
    for (int i = 0; i < 8; i++) { float x = (float)v0[i]; nb += x * x; }
#pragma unroll
    for (int i = 0; i < 8; i++) { float x = (float)v1[i]; nb += x * x; }
    nb += __shfl_xor(nb, 1, 64);
    nb += __shfl_xor(nb, 2, 64);
    const float rinv = 1.f / fmaxf(sqrtf(nb), 1e-8f);

    float sv[25];
#pragma unroll
    for (int i = 0; i < 25; i++)
      sv[i] = (float)rb[row][128 + s * 25 + i] * rinv;
    float mx = sv[0];
#pragma unroll
    for (int i = 1; i < 25; i++) mx = fmaxf(mx, sv[i]);
    mx = fmaxf(mx, __shfl_xor(mx, 1, 64));
    mx = fmaxf(mx, __shfl_xor(mx, 2, 64));
    float es = 0.f;
#pragma unroll
    for (int i = 0; i < 25; i++) { sv[i] = __expf(sv[i] - mx); es += sv[i]; }
    es += __shfl_xor(es, 1, 64);
    es += __shfl_xor(es, 2, 64);
    const float isum = 1.f / es;

    // category dots BEFORE overwriting (reads cols 64..127, disjoint anyway)
    const int ci = cidx[row0 + row];
    const float* kp = catk + (size_t)ci * (CKSZ * MD) + s * 16;
    f16x8 c0 = *(const f16x8*)&rb[row][64 + s * 16];
    f16x8 c1 = *(const f16x8*)&rb[row][64 + s * 16 + 8];
    float cqf[16];
#pragma unroll
    for (int i = 0; i < 8; i++) { cqf[i] = (float)c0[i]; cqf[8 + i] = (float)c1[i]; }
    float t[5];
#pragma unroll
    for (int sl = 0; sl < 5; sl++) {
      f32x4 k0 = *(const f32x4*)(kp + sl * MD);
      f32x4 k1 = *(const f32x4*)(kp + sl * MD + 4);
      f32x4 k2 = *(const f32x4*)(kp + sl * MD + 8);
      f32x4 k3 = *(const f32x4*)(kp + sl * MD + 12);
      float a = 0.f;
#pragma unroll
      for (int i = 0; i < 4; i++) a += cqf[i] * k0[i];
#pragma unroll
      for (int i = 0; i < 4; i++) a += cqf[4 + i] * k1[i];
#pragma unroll
      for (int i = 0; i < 4; i++) a += cqf[8 + i] * k2[i];
#pragma unroll
      for (int i = 0; i < 4; i++) a += cqf[12 + i] * k3[i];
      a += __shfl_xor(a, 1, 64);
      a += __shfl_xor(a, 2, 64);
      t[sl] = a;
    }

    // in-place: attn over own sims slice (no cross-thread readers afterwards)
#pragma unroll
    for (int i = 0; i < 25; i++)
      rb[row][128 + s * 25 + i] = (f16)(sv[i] * isum);

    if (s == 0) {
      float m5 = fmaxf(fmaxf(fmaxf(t[0], t[1]), fmaxf(t[2], t[3])), t[4]);
      float e0 = __expf(t[0] - m5), e1 = __expf(t[1] - m5), e2 = __expf(t[2] - m5),
            e3 = __expf(t[3] - m5), e4 = __expf(t[4] - m5);
      float ics = 1.f / (e0 + e1 + e2 + e3 + e4);
      float* cwr = cwg + (size_t)(row0 + row) * 5;
      cwr[0] = e0 * ics; cwr[1] = e1 * ics; cwr[2] = e2 * ics;
      cwr[3] = e3 * ics; cwr[4] = e4 * ics;
      csg[row0 + row] = ci * CKSZ;
    }
  }
  __syncthreads();

  // ---- stage out: A2[row][k] = k<100 ? rb[row][128+k] : 0 ----
  {
    const int row = tid >> 2, s = tid & 3;
    f16 tmp[32];
#pragma unroll
    for (int i = 0; i < 32; i++) {
      const int k = s * 32 + i;
      tmp[i] = (k < MSZ) ? rb[row][128 + k] : (f16)0.f;
    }
    f16* dst = A2 + (size_t)(row0 + row) * K2 + s * 32;
#pragma unroll
    for (int i = 0; i < 4; i++)
      *(f16x8*)(dst + i * 8) = *(const f16x8*)&tmp[i * 8];
  }
}

// ===== GEMM2: out = A2 @ B2^T + bout + rank-5 cat gather (round-9/10) =====
__global__ __launch_bounds__(512) void k_gemm2(const f16* __restrict__ A2,
    const f16* __restrict__ B2p, const float* __restrict__ cwg,
    const int* __restrict__ csg, const f16* __restrict__ C2cat,
    const float* __restrict__ bout, float* __restrict__ out) {
  __shared__ f16 As[128][136];
  __shared__ float cws[128][5];
  __shared__ int csi[128];
  const int tid = threadIdx.x;
  const int lane = tid & 63, wid = tid >> 6;
  const int wm = wid & 1, wn = wid >> 1;
  const int l15 = lane & 15, l4 = lane >> 4;
  const int row0 = blockIdx.x * 128;
  const int col0 = blockIdx.y * 256;

  {
    const int r = tid >> 2, seg = tid & 3;
    const f16* src = A2 + (size_t)(row0 + r) * K2 + seg * 32;
#pragma unroll
    for (int i = 0; i < 4; i++)
      *(f16x8*)&As[r][seg * 32 + i * 8] = *(const f16x8*)(src + i * 8);
  }
  if (tid < 128) {
#pragma unroll
    for (int i = 0; i < 5; i++) cws[tid][i] = cwg[(size_t)(row0 + tid) * 5 + i];
    csi[tid] = csg[row0 + tid];
  }
  __syncthreads();

  f32x4 acc[4][4];
#pragma unroll
  for (int i = 0; i < 4; i++)
#pragma unroll
    for (int j = 0; j < 4; j++) acc[i][j] = (f32x4){0.f, 0.f, 0.f, 0.f};

#pragma unroll
  for (int ks = 0; ks < 8; ks++) {
    f16x4 af[4], bf[4];
#pragma unroll
    for (int mi = 0; mi < 4; mi++)
      af[mi] = *(const f16x4*)&As[wm * 64 + mi * 16 + l15][ks * 16 + 4 * l4];
#pragma unroll
    for (int ni = 0; ni < 4; ni++)
      bf[ni] = *(const f16x4*)(B2p +
        (((size_t)(blockIdx.y * 16 + wn * 4 + ni) * 8 + ks) * 64 + lane) * 4);
#pragma unroll
    for (int mi = 0; mi < 4; mi++)
#pragma unroll
      for (int ni = 0; ni < 4; ni++)
        acc[mi][ni] = mfma16(af[mi], bf[ni], acc[mi][ni]);
  }

  float bs[4];
#pragma unroll
  for (int ni = 0; ni < 4; ni++) bs[ni] = bout[col0 + wn * 64 + ni * 16 + l15];
#pragma unroll
  for (int mi = 0; mi < 4; mi++) {
#pragma unroll
    for (int j = 0; j < 4; j++) {
      const int r = wm * 64 + mi * 16 + 4 * l4 + j;
      const int cb = csi[r];
      const float w0 = cws[r][0], w1 = cws[r][1], w2 = cws[r][2],
                  w3 = cws[r][3], w4 = cws[r][4];
      const f16* cp = C2cat + (size_t)cb * ODIM + col0 + wn * 64 + l15;
#pragma unroll
      for (int ni = 0; ni < 4; ni++) {
        const int col = col0 + wn * 64 + ni * 16 + l15;
        const f16* cpn = cp + ni * 16;
        float v = acc[mi][ni][j] + bs[ni];
        v += w0 * (float)cpn[0]
           + w1 * (float)cpn[ODIM]
           + w2 * (float)cpn[2 * ODIM]
           + w3 * (float)cpn[3 * ODIM]
           + w4 * (float)cpn[4 * ODIM];
        out[(size_t)(row0 + r) * ODIM + col] = v;
      }
    }
  }
}

extern "C" void kernel_launch(void* const* d_in, const int* in_sizes, int n_in,
                              void* d_out, int out_size, void* d_ws, size_t ws_size,
                              hipStream_t stream) {
  const float* query = (const float*)d_in[0];
  const int*   cidx  = (const int*)d_in[1];
  const float* Wb    = (const float*)d_in[2];
  const float* bb    = (const float*)d_in[3];
  const float* Wc    = (const float*)d_in[4];
  const float* bc    = (const float*)d_in[5];
  const float* bkeys = (const float*)d_in[6];
  const float* bvals = (const float*)d_in[7];
  const float* ckeys = (const float*)d_in[8];
  const float* cvals = (const float*)d_in[9];
  const float* Wo    = (const float*)d_in[10];
  const float* bo    = (const float*)d_in[11];
  float* out = (float*)d_out;

  char* ws = (char*)d_ws;
  f16*   A2    = (f16*)(ws);                          // 65536*128*2 = 16777216
  float* cwg   = (float*)(ws + 16777216);             // 65536*5*4   = 1310720
  int*   csg   = (int*)(ws + 18087936);               // 65536*4     = 262144
  f16*   B1    = (f16*)(ws + 18350080);               // 256*512*2   = 262144
  f16*   B2p   = (f16*)(ws + 18612224);               // 16384*4*2   = 131072
  f16*   C2cat = (f16*)(ws + 18743296);               // 175*512*2   = 179200
  float* bias1 = (float*)(ws + 18922496);             // 1024

  const int prep_ids = N1 * INDIM + 16384 + NSLOT * ODIM;  // 237056
  k_prep<<<dim3((prep_ids + 255) / 256), 256, 0, stream>>>(
      Wb, bb, Wc, bc, bkeys, bvals, cvals, Wo, B1, bias1, B2p, C2cat);
  k_g1mid<<<dim3(BATCH / 128), 512, 0, stream>>>(
      query, B1, bias1, cidx, ckeys, A2, cwg, csg);
  k_gemm2<<<dim3(BATCH / 128, 2), 512, 0, stream>>>(A2, B2p, cwg, csg, C2cat, bo, out);
}